// Round 11
// baseline (224.995 us; speedup 1.0000x reference)
//
#include <hip/hip_runtime.h>
#include <cstddef>

// Problem constants
constexpr int B_ = 4, H_ = 96, W_ = 96, C_ = 192, QKVC = 576;
constexpr int NPIX = B_ * H_ * W_;           // 36864
// exp(s*SCALE) = 2^(s*C2), C2 = 32^-0.5 * log2(e)
constexpr float C2 = 0.25503486208385085f;

typedef __attribute__((ext_vector_type(8))) short bf16x8;
typedef __attribute__((ext_vector_type(4))) float f32x4;
typedef unsigned short ushort_t;

__device__ __forceinline__ unsigned short f2bf(float f) {
    unsigned int u = __builtin_bit_cast(unsigned int, f);
    u += 0x7fffu + ((u >> 16) & 1u);       // round-to-nearest-even
    return (unsigned short)(u >> 16);
}
__device__ __forceinline__ float bf2f(unsigned short h) {
    unsigned int u = ((unsigned int)h) << 16;
    return __builtin_bit_cast(float, u);
}
__device__ __forceinline__ unsigned int pack2(unsigned short a, unsigned short b) {
    return (unsigned int)a | ((unsigned int)b << 16);   // a -> low half
}
__device__ __forceinline__ float fexp2(float x) {
#if __has_builtin(__builtin_amdgcn_exp2f)
    return __builtin_amdgcn_exp2f(x);
#else
    return __expf(x * 0.6931471805599453f);
#endif
}

// ---------------------------------------------------------------------------
// vT layout (R10, verified): per slice ((b*96+i)*6 + g*2 + h) of 3072
// ushorts, element (dd, jj) lives at (jj>>2)*128 + dd*4 + (jj&3).
// ---------------------------------------------------------------------------

// ---------------------------------------------------------------------------
// convert_all: x -> xh bf16; w_qkv -> wqt[576][192]; w_proj -> wpt_h/wpt_l.
// ---------------------------------------------------------------------------
__global__ __launch_bounds__(256) void convert_all_kernel(
    const float* __restrict__ x, const float* __restrict__ w_qkv,
    const float* __restrict__ w_proj,
    ushort_t* __restrict__ xh, ushort_t* __restrict__ wqt,
    ushort_t* __restrict__ wpt_h, ushort_t* __restrict__ wpt_l, int n4)
{
    int i = blockIdx.x * 256 + threadIdx.x;
    if (i < n4) {
        float4 v = ((const float4*)x)[i];
        uint2 p;
        p.x = pack2(f2bf(v.x), f2bf(v.y));
        p.y = pack2(f2bf(v.z), f2bf(v.w));
        ((uint2*)xh)[i] = p;
        return;
    }
    int idx = i - n4;
    if (idx < 576 * 192) {
        int n = idx / 192, k = idx - n * 192;
        wqt[idx] = f2bf(w_qkv[(size_t)k * 576 + n]);
    } else {
        int i2 = idx - 576 * 192;
        if (i2 < 192 * 192) {
            int n = i2 / 192, k = i2 - n * 192;
            float v = w_proj[(size_t)k * 192 + n];
            unsigned short h = f2bf(v);
            wpt_h[i2] = h;
            wpt_l[i2] = f2bf(v - bf2f(h));
        }
    }
}

// ---------------------------------------------------------------------------
// MFMA bf16 GEMM, tile 64xNTx64. A bf16 [M][K], B pre-transposed Bt[n][k].
// BSPLIT: 2 passes A*(Bh+Bl). OUTBF: bf16 C. VT (NT=192): tiled-layout vT
// stores (R10-verified, coalesced 128B runs).
//
// R11 k-loop: T14 issue-early placement. Structure per step s:
//   commit(s): vmcnt-wait regs(s), ds_write into the (single) LDS buffer
//   __syncthreads()                  // writes visible; prev compute done
//   stage_issue(s+1)                 // loads -> regs, NO wait  [AFTER the
//                                    //  barrier — R6 issued them BEFORE,
//                                    //  so the barrier's vmcnt(0) drain
//                                    //  serialized them; 2x regression]
//   compute(s)                       // overlaps the in-flight loads
//   __syncthreads()                  // drains residual load latency
// Same two barriers/iter, same single buffer, same lambdas as R6 (which
// PASSED correctness) — only the load-issue point moved.
// Grid is XCD-swizzled (gridDim.x must be a multiple of 8).
// ---------------------------------------------------------------------------
template<bool BSPLIT, bool OUTBF, bool VT, int NT>
__global__ __launch_bounds__(256) void gemm_mfma2_kernel(
    const ushort_t* __restrict__ A,
    const ushort_t* __restrict__ Bt_h, const ushort_t* __restrict__ Bt_l,
    const float* __restrict__ bias, void* __restrict__ Cout,
    ushort_t* __restrict__ vTout, int M, int N, int K)
{
    constexpr int NPB = BSPLIT ? 2 : 1;
    constexpr int NI = NT / 32;            // 16-wide frags per wave (n-dim)
    __shared__ __align__(16) ushort_t As[8 * 64 * 8];
    __shared__ __align__(16) ushort_t Bs[NPB][8 * NT * 8];

    const int tid = threadIdx.x;
    const int lane = tid & 63;
    const int w = tid >> 6;
    const int wm = (w & 1) * 32;
    const int wn = (w >> 1) * (NT / 2);
    const int fm = lane & 15;
    const int fq = lane >> 4;

    // bijective XCD-contiguity swizzle
    const int phys = blockIdx.x;
    const int bid = (phys & 7) * (int)(gridDim.x >> 3) + (phys >> 3);
    const int ntiles = N / NT;
    const int m0 = (bid / ntiles) * 64;
    const int n0 = (bid % ntiles) * NT;

    // per-thread staging slot map (loop-invariant): rows sa_m, sa_m+32
    const int sa_m  = tid >> 3;
    const int sa_kc = tid & 7;

    f32x4 acc[2][NI];
    #pragma unroll
    for (int mi = 0; mi < 2; ++mi)
        #pragma unroll
        for (int ni = 0; ni < NI; ++ni)
            acc[mi][ni] = (f32x4){0.f, 0.f, 0.f, 0.f};

    // staging register buffers (held across compute; ~32 VGPRs)
    uint4 au[2];
    uint4 bu[NI];
    uint4 blu[BSPLIT ? NI : 1];

    const int NS = K / 64;

    auto stage_issue = [&](int k0) {
        #pragma unroll
        for (int it = 0; it < 2; ++it)
            au[it] = *(const uint4*)(A + (size_t)(m0 + sa_m + it * 32) * K + k0 + sa_kc * 8);
        #pragma unroll
        for (int it = 0; it < NI; ++it) {
            bu[it] = *(const uint4*)(Bt_h + (size_t)(n0 + sa_m + it * 32) * K + k0 + sa_kc * 8);
            if constexpr (BSPLIT)
                blu[it] = *(const uint4*)(Bt_l + (size_t)(n0 + sa_m + it * 32) * K + k0 + sa_kc * 8);
        }
    };
    auto commit = [&]() {
        #pragma unroll
        for (int it = 0; it < 2; ++it)
            *(uint4*)(&As[0] + (sa_kc * 64 + ((sa_m + it * 32) ^ sa_kc)) * 8) = au[it];
        #pragma unroll
        for (int it = 0; it < NI; ++it) {
            const int phys_g = sa_kc * NT + ((sa_m + it * 32) ^ sa_kc);
            *(uint4*)(&Bs[0][0] + phys_g * 8) = bu[it];
            if constexpr (BSPLIT)
                *(uint4*)(&Bs[NPB - 1][0] + phys_g * 8) = blu[it];
        }
    };

    stage_issue(0);
    for (int s = 0; s < NS; ++s) {
        commit();                          // waits its own loads (staggered)
        __syncthreads();                   // LDS visible; prev compute done
        if (s + 1 < NS) stage_issue((s + 1) * 64);  // fly during compute(s)

        #pragma unroll
        for (int kt2 = 0; kt2 < 2; ++kt2) {
            const int kc = kt2 * 4 + fq;
            bf16x8 ah[2], bh[NI];
            #pragma unroll
            for (int mi = 0; mi < 2; ++mi)
                ah[mi] = *(const bf16x8*)(&As[0] + (kc * 64 + ((wm + mi * 16 + fm) ^ kc)) * 8);
            #pragma unroll
            for (int ni = 0; ni < NI; ++ni)
                bh[ni] = *(const bf16x8*)(&Bs[0][0] + (kc * NT + ((wn + ni * 16 + fm) ^ kc)) * 8);
            #pragma unroll
            for (int mi = 0; mi < 2; ++mi)
                #pragma unroll
                for (int ni = 0; ni < NI; ++ni)
                    acc[mi][ni] = __builtin_amdgcn_mfma_f32_16x16x32_bf16(
                        ah[mi], bh[ni], acc[mi][ni], 0, 0, 0);
            if constexpr (BSPLIT) {
                bf16x8 bl[NI];
                #pragma unroll
                for (int ni = 0; ni < NI; ++ni)
                    bl[ni] = *(const bf16x8*)(&Bs[NPB - 1][0] + (kc * NT + ((wn + ni * 16 + fm) ^ kc)) * 8);
                #pragma unroll
                for (int mi = 0; mi < 2; ++mi)
                    #pragma unroll
                    for (int ni = 0; ni < NI; ++ni)
                        acc[mi][ni] = __builtin_amdgcn_mfma_f32_16x16x32_bf16(
                            ah[mi], bl[ni], acc[mi][ni], 0, 0, 0);
            }
        }
        if (s + 1 < NS) __syncthreads();   // compute done before overwrite;
                                           // drains loads(s+1) (mostly done)
    }

    // epilogue: C/D col=lane&15, row=fq*4+reg
    #pragma unroll
    for (int ni = 0; ni < NI; ++ni) {
        const int lcol = wn + ni * 16 + fm;
        const int col = n0 + lcol;
        const float bv = bias[col];
        const int vl = lcol - 128;               // v-channel index (if >=0)
        #pragma unroll
        for (int mi = 0; mi < 2; ++mi) {
            const int rbase = m0 + wm + mi * 16 + fq * 4;
            if constexpr (VT) {
                if (vl >= 0) {
                    // tiled store: 4 consecutive jj at fixed dd -> one 8B
                    // tile at (jj>>2)*128 + dd*4; fm-lanes contiguous 128B.
                    int bb = rbase / 9216;
                    int rem = rbase - bb * 9216;
                    int ii = rem / 96;
                    int jj = rem - ii * 96;
                    int hh = vl >> 5, dd = vl & 31;
                    unsigned long long pk =
                          (unsigned long long)f2bf(acc[mi][ni][0] + bv)
                        | ((unsigned long long)f2bf(acc[mi][ni][1] + bv) << 16)
                        | ((unsigned long long)f2bf(acc[mi][ni][2] + bv) << 32)
                        | ((unsigned long long)f2bf(acc[mi][ni][3] + bv) << 48);
                    *(unsigned long long*)(vTout
                        + ((size_t)((bb * 96 + ii) * 6) + (n0 / 192) * 2 + hh) * 3072
                        + (size_t)(jj >> 2) * 128 + dd * 4) = pk;
                    continue;                    // v never read from qkvh
                }
            }
            #pragma unroll
            for (int r = 0; r < 4; ++r) {
                float val = acc[mi][ni][r] + bv;
                if constexpr (OUTBF)
                    ((ushort_t*)Cout)[(size_t)(rbase + r) * N + col] = f2bf(val);
                else
                    ((float*)Cout)[(size_t)(rbase + r) * N + col] = val;
            }
        }
    }
}

// ---------------------------------------------------------------------------
// Neighborhood attention v8t — row-paired hybrid, tiled-vT (UNCHANGED from
// R10, verified).
// ---------------------------------------------------------------------------
__global__ __launch_bounds__(384, 5) void na2d_kernel(
    const ushort_t* __restrict__ qkv, const ushort_t* __restrict__ vT,
    ushort_t* __restrict__ attn)
{
    __shared__ ushort_t Kb[2][96 * 40];    // [col][pad40], chunk-XOR swizzle
    __shared__ ushort_t Vtb[2][3072];      // linear tiled slice copy

    // bijective XCD-contiguity swizzle (1152 = 8 * 144)
    int phys = blockIdx.x;
    int idx = (phys & 7) * 144 + (phys >> 3);

    const int g = idx % 3; idx /= 3;       // g fastest: XCD load balance
    const int h = idx & 1; idx >>= 1;
    const int R = idx % 48;
    const int b = idx / 48;
    const int i0 = R * 2, i1 = i0 + 1;

    const int K = 7 + 2 * g, cc = K >> 1;
    int si0 = i0 - cc; if (si0 < 0) si0 = 0; if (si0 > H_ - K) si0 = H_ - K;
    int si1 = i1 - cc; if (si1 < 0) si1 = 0; if (si1 > H_ - K) si1 = H_ - K;
    const int off1 = si1 - si0;            // 0 or 1
    const int NTr = K + off1;              // staged rows

    const int tid = threadIdx.x;
    const int w = tid >> 6, lane = tid & 63;
    const int fm = lane & 15, fq = lane >> 4;
    const int pixbase = w * 16;

    int cb = (pixbase - cc) & ~7;          // aligned union-window base
    if (cb < 0) cb = 0; if (cb > 64) cb = 64;
    const int col0 = cb + fm, col1 = cb + 16 + fm;

    // per-lane softmax mask -> exp2 bias; depends only on j -> row-shared
    const int jlane = pixbase + fm;
    int sjl = jlane - cc; if (sjl < 0) sjl = 0; if (sjl > W_ - K) sjl = W_ - K;
    float b0[4], b1[4];
    #pragma unroll
    for (int r = 0; r < 4; ++r) {
        b0[r] = ((unsigned)(cb + fq * 4 + r - sjl)      < (unsigned)K) ? 0.f : -1e30f;
        b1[r] = ((unsigned)(cb + 16 + fq * 4 + r - sjl) < (unsigned)K) ? 0.f : -1e30f;
    }

    // Q B-frags for both rows: pixel j=jlane, dims fq*8..+8 (loop-invariant)
    const size_t rowstride = (size_t)W_ * QKVC;    // ushorts per image row
    const size_t qoff = (size_t)jlane * QKVC + g * 192 + h * 32 + fq * 8;
    const bf16x8 qfragA = *(const bf16x8*)(qkv + (size_t)(b * H_ + i0) * rowstride + qoff);
    const bf16x8 qfragB = *(const bf16x8*)(qkv + (size_t)(b * H_ + i1) * rowstride + qoff);

    // staging maps (coalesced: addr = base + tid*16B for both)
    const int scol = tid >> 2, sch = tid & 3;
    const size_t kgoff = (size_t)scol * QKVC + g * 192 + 64 + h * 32 + sch * 8;
    const int klds = scol * 40 + ((sch ^ (scol & 3)) << 3);
    const size_t vslice = ((size_t)((b * H_ + si0) * 6) + g * 2 + h) * 3072;

    f32x4 ya0 = {0.f,0.f,0.f,0.f}, ya1 = {0.f,0.f,0.f,0.f};
    f32x4 yb0 = {0.f,0.f,0.f,0.f}, yb1 = {0.f,0.f,0.f,0.f};
    float lsumA = 0.f, lsumB = 0.f;

    uint4 kv = *(const uint4*)(qkv + (size_t)(b * H_ + si0) * rowstride + kgoff);
    uint4 vv = *(const uint4*)(vT + vslice + (size_t)tid * 8);

    // shared softmax+PV body (verified v7 arithmetic)
    auto softmax_pv = [&](const f32x4& s0, const f32x4& s1, float& lsum,
                          const bf16x8& cv0, const bf16x8& cv1,
                          f32x4& y0, f32x4& y1) {
        unsigned short p00 = f2bf(fexp2(fmaf(s0[0], C2, b0[0])));
        unsigned short p01 = f2bf(fexp2(fmaf(s0[1], C2, b0[1])));
        unsigned short p02 = f2bf(fexp2(fmaf(s0[2], C2, b0[2])));
        unsigned short p03 = f2bf(fexp2(fmaf(s0[3], C2, b0[3])));
        unsigned short p10 = f2bf(fexp2(fmaf(s1[0], C2, b1[0])));
        unsigned short p11 = f2bf(fexp2(fmaf(s1[1], C2, b1[1])));
        unsigned short p12 = f2bf(fexp2(fmaf(s1[2], C2, b1[2])));
        unsigned short p13 = f2bf(fexp2(fmaf(s1[3], C2, b1[3])));
        lsum += (bf2f(p00) + bf2f(p01)) + (bf2f(p02) + bf2f(p03))
              + (bf2f(p10) + bf2f(p11)) + (bf2f(p12) + bf2f(p13));
        const bf16x8 pa = __builtin_bit_cast(bf16x8, (uint4){
            pack2(p00, p01), pack2(p02, p03),
            pack2(p10, p11), pack2(p12, p13)});
        y0 = __builtin_amdgcn_mfma_f32_16x16x32_bf16(pa, cv0, y0, 0, 0, 0);
        y1 = __builtin_amdgcn_mfma_f32_16x16x32_bf16(pa, cv1, y1, 0, 0, 0);
    };

    for (int t = 0; t < NTr; ++t) {
        *(uint4*)&Kb[t & 1][klds] = kv;
        *(uint4*)&Vtb[t & 1][tid * 8] = vv;
        if (t + 1 < NTr) {
            kv = *(const uint4*)(qkv + (size_t)(b * H_ + si0 + t + 1) * rowstride + kgoff);
            vv = *(const uint4*)(vT + vslice + (size_t)(t + 1) * 18432 + (size_t)tid * 8);
        }
        __syncthreads();

        // ---- shared LDS fragment reads ----
        bf16x8 kf0 = *(const bf16x8*)&Kb[t & 1][col0 * 40 + ((fq ^ (col0 & 3)) << 3)];
        bf16x8 kf1 = *(const bf16x8*)&Kb[t & 1][col1 * 40 + ((fq ^ (col1 & 3)) << 3)];
        // V B-frags from the tiled slice: cell (cb>>2)+fq (+4 for cols+16),
        // dims fm and fm+16 -> 4x ds_read_b64.
        const ushort_t* vbase = &Vtb[t & 1][((cb >> 2) + fq) * 128 + fm * 4];
        uint2 va0 = *(const uint2*)(vbase);            // cols cb+4fq..+3,  dim fm
        uint2 va1 = *(const uint2*)(vbase + 512);      // cols cb+16+4fq..+3, dim fm
        uint2 va2 = *(const uint2*)(vbase + 64);       // cols cb+4fq..+3,  dim fm+16
        uint2 va3 = *(const uint2*)(vbase + 512 + 64); // cols cb+16+4fq..+3, dim fm+16
        const bf16x8 cv0 = __builtin_bit_cast(bf16x8, (uint4){va0.x, va0.y, va1.x, va1.y});
        const bf16x8 cv1 = __builtin_bit_cast(bf16x8, (uint4){va2.x, va2.y, va3.x, va3.y});

        // ---- row A (valid t: 0..K-1) — wave-uniform guard ----
        if (t < K) {
            f32x4 s0 = __builtin_amdgcn_mfma_f32_16x16x32_bf16(
                kf0, qfragA, (f32x4){0.f, 0.f, 0.f, 0.f}, 0, 0, 0);
            f32x4 s1 = __builtin_amdgcn_mfma_f32_16x16x32_bf16(
                kf1, qfragA, (f32x4){0.f, 0.f, 0.f, 0.f}, 0, 0, 0);
            softmax_pv(s0, s1, lsumA, cv0, cv1, ya0, ya1);
        }
        // ---- row B (valid t: off1..off1+K-1; t<NTr implies t<off1+K) ----
        if (t >= off1) {
            f32x4 s0 = __builtin_amdgcn_mfma_f32_16x16x32_bf16(
                kf0, qfragB, (f32x4){0.f, 0.f, 0.f, 0.f}, 0, 0, 0);
            f32x4 s1 = __builtin_amdgcn_mfma_f32_16x16x32_bf16(
                kf1, qfragB, (f32x4){0.f, 0.f, 0.f, 0.f}, 0, 0, 0);
            softmax_pv(s0, s1, lsumB, cv0, cv1, yb0, yb1);
        }
    }

    // ---- reduce l + store, per row ----
    lsumA += __shfl_xor(lsumA, 16);
    lsumA += __shfl_xor(lsumA, 32);        // l[j=fm], uniform over fq
    lsumB += __shfl_xor(lsumB, 16);
    lsumB += __shfl_xor(lsumB, 32);

    #pragma unroll
    for (int r = 0; r < 4; ++r) {
        const int j = pixbase + fq * 4 + r;
        const float lA = __shfl(lsumA, fq * 4 + r);
        const float lB = __shfl(lsumB, fq * 4 + r);
        const float invA = 1.f / lA, invB = 1.f / lB;
        const size_t oA = (size_t)((b * H_ + i0) * W_ + j) * C_ + g * 64 + h * 32 + fm;
        const size_t oB = (size_t)((b * H_ + i1) * W_ + j) * C_ + g * 64 + h * 32 + fm;
        attn[oA]      = f2bf(ya0[r] * invA);
        attn[oA + 16] = f2bf(ya1[r] * invA);
        attn[oB]      = f2bf(yb0[r] * invB);
        attn[oB + 16] = f2bf(yb1[r] * invB);
    }
}

// ---------------------------------------------------------------------------
extern "C" void kernel_launch(void* const* d_in, const int* in_sizes, int n_in,
                              void* d_out, int out_size, void* d_ws, size_t ws_size,
                              hipStream_t stream)
{
    const float* x      = (const float*)d_in[0];
    const float* w_qkv  = (const float*)d_in[1];
    const float* b_qkv  = (const float*)d_in[2];
    const float* w_proj = (const float*)d_in[3];
    const float* b_proj = (const float*)d_in[4];
    float* out = (float*)d_out;

    // Workspace: [qkvh 42.5MB][xh/attn bf16 14.2MB aliased][weights][vT 14.2MB]
    char* ws = (char*)d_ws;
    ushort_t* qkvh  = (ushort_t*)ws;
    char*     reg1  = ws + (size_t)NPIX * QKVC * 2;
    ushort_t* xh    = (ushort_t*)reg1;            // dead after GEMM1
    ushort_t* attn  = (ushort_t*)reg1;            // aliases xh
    char*     wbase = reg1 + (size_t)NPIX * C_ * 2;
    ushort_t* wqt   = (ushort_t*)wbase;
    ushort_t* wpt_h = (ushort_t*)(wbase + 576 * 192 * 2);
    ushort_t* wpt_l = (ushort_t*)(wbase + 576 * 192 * 2 + 192 * 192 * 2);
    ushort_t* vT    = (ushort_t*)(wbase + 576 * 192 * 2 + 2 * 192 * 192 * 2);

    // 0) all fp32->bf16 conversions in one dispatch
    convert_all_kernel<<<7488, 256, 0, stream>>>(
        x, w_qkv, w_proj, xh, wqt, wpt_h, wpt_l, NPIX * C_ / 4);

    // 1) qkv = xh @ w_qkv + b_qkv (bf16, q/k only) + tiled vT (coalesced)
    //    grid 1728 = 8 * 216 (XCD-swizzled); T14 issue-early k-loop
    gemm_mfma2_kernel<false, true, true, 192><<<(NPIX / 64) * (QKVC / 192), 256, 0, stream>>>(
        xh, wqt, nullptr, b_qkv, qkvh, vT, NPIX, QKVC, C_);

    // 2) neighborhood attention (row-paired hybrid, tiled-vT): 1152 x 384
    na2d_kernel<<<1152, 384, 0, stream>>>(qkvh, vT, attn);

    // 3) out = attn @ w_proj + b_proj (A bf16, B split-bf16 2-pass, N-tile 96)
    //    grid 1152 = 8 * 144 (XCD-swizzled); T14 issue-early k-loop
    gemm_mfma2_kernel<true, false, false, 96><<<(NPIX / 64) * (C_ / 96), 256, 0, stream>>>(
        attn, wpt_h, wpt_l, b_proj, out, nullptr, NPIX, C_, C_);
}

// Round 12
// 150.724 us; speedup vs baseline: 1.4928x; 1.4928x over previous
//
#include <hip/hip_runtime.h>
#include <cstddef>

// Problem constants
constexpr int B_ = 4, H_ = 96, W_ = 96, C_ = 192, QKVC = 576;
constexpr int NPIX = B_ * H_ * W_;           // 36864
// exp(s*SCALE) = 2^(s*C2), C2 = 32^-0.5 * log2(e)
constexpr float C2 = 0.25503486208385085f;

typedef __attribute__((ext_vector_type(8))) short bf16x8;
typedef __attribute__((ext_vector_type(4))) float f32x4;
typedef unsigned short ushort_t;

__device__ __forceinline__ unsigned short f2bf(float f) {
    unsigned int u = __builtin_bit_cast(unsigned int, f);
    u += 0x7fffu + ((u >> 16) & 1u);       // round-to-nearest-even
    return (unsigned short)(u >> 16);
}
__device__ __forceinline__ float bf2f(unsigned short h) {
    unsigned int u = ((unsigned int)h) << 16;
    return __builtin_bit_cast(float, u);
}
__device__ __forceinline__ unsigned int pack2(unsigned short a, unsigned short b) {
    return (unsigned int)a | ((unsigned int)b << 16);   // a -> low half
}
__device__ __forceinline__ float fexp2(float x) {
#if __has_builtin(__builtin_amdgcn_exp2f)
    return __builtin_amdgcn_exp2f(x);
#else
    return __expf(x * 0.6931471805599453f);
#endif
}

// ---------------------------------------------------------------------------
// vT layout (R10, verified): per slice ((b*96+i)*6 + g*2 + h) of 3072
// ushorts, element (dd, jj) lives at (jj>>2)*128 + dd*4 + (jj&3).
// ---------------------------------------------------------------------------

// ---------------------------------------------------------------------------
// convert_all: x -> xh bf16; w_qkv -> wqt[576][192]; w_proj -> wpt_h/wpt_l.
// ---------------------------------------------------------------------------
__global__ __launch_bounds__(256) void convert_all_kernel(
    const float* __restrict__ x, const float* __restrict__ w_qkv,
    const float* __restrict__ w_proj,
    ushort_t* __restrict__ xh, ushort_t* __restrict__ wqt,
    ushort_t* __restrict__ wpt_h, ushort_t* __restrict__ wpt_l, int n4)
{
    int i = blockIdx.x * 256 + threadIdx.x;
    if (i < n4) {
        float4 v = ((const float4*)x)[i];
        uint2 p;
        p.x = pack2(f2bf(v.x), f2bf(v.y));
        p.y = pack2(f2bf(v.z), f2bf(v.w));
        ((uint2*)xh)[i] = p;
        return;
    }
    int idx = i - n4;
    if (idx < 576 * 192) {
        int n = idx / 192, k = idx - n * 192;
        wqt[idx] = f2bf(w_qkv[(size_t)k * 576 + n]);
    } else {
        int i2 = idx - 576 * 192;
        if (i2 < 192 * 192) {
            int n = i2 / 192, k = i2 - n * 192;
            float v = w_proj[(size_t)k * 192 + n];
            unsigned short h = f2bf(v);
            wpt_h[i2] = h;
            wpt_l[i2] = f2bf(v - bf2f(h));
        }
    }
}

// ---------------------------------------------------------------------------
// MFMA bf16 GEMM, tile 64xNTx64 — R10-verified structure (DIRECT global->LDS
// staging inside the barrier pair; reg-staging regressed 2x in BOTH R6 and
// R11 — permanently rejected). A bf16 [M][K], B pre-transposed Bt[n][k].
// BSPLIT: 2 passes A*(Bh+Bl). OUTBF: bf16 C. VT: v-channels (global col%192
// in 128..191) go ONLY to tiled vT (R10-verified coalesced 8B-tile stores).
// R12: NT=96 supported for GEMM1 -> LDS 20KB -> 8 blocks/CU residency
// (was 32KB -> 5); v-channel test generalized via cin192 = (n0%192)+lcol
// (NT=192 behavior identical since n0%192==0 there).
// Grid is XCD-swizzled (gridDim.x must be a multiple of 8).
// ---------------------------------------------------------------------------
template<bool BSPLIT, bool OUTBF, bool VT, int NT>
__global__ __launch_bounds__(256) void gemm_mfma2_kernel(
    const ushort_t* __restrict__ A,
    const ushort_t* __restrict__ Bt_h, const ushort_t* __restrict__ Bt_l,
    const float* __restrict__ bias, void* __restrict__ Cout,
    ushort_t* __restrict__ vTout, int M, int N, int K)
{
    constexpr int NPB = BSPLIT ? 2 : 1;
    constexpr int NI = NT / 32;            // 16-wide frags per wave (n-dim)
    __shared__ __align__(16) ushort_t As[8 * 64 * 8];
    __shared__ __align__(16) ushort_t Bs[NPB][8 * NT * 8];

    const int tid = threadIdx.x;
    const int lane = tid & 63;
    const int w = tid >> 6;
    const int wm = (w & 1) * 32;
    const int wn = (w >> 1) * (NT / 2);
    const int fm = lane & 15;
    const int fq = lane >> 4;

    // bijective XCD-contiguity swizzle
    const int phys = blockIdx.x;
    const int bid = (phys & 7) * (int)(gridDim.x >> 3) + (phys >> 3);
    const int ntiles = N / NT;
    const int m0 = (bid / ntiles) * 64;
    const int n0 = (bid % ntiles) * NT;

    f32x4 acc[2][NI];
    #pragma unroll
    for (int mi = 0; mi < 2; ++mi)
        #pragma unroll
        for (int ni = 0; ni < NI; ++ni)
            acc[mi][ni] = (f32x4){0.f, 0.f, 0.f, 0.f};

    for (int k0 = 0; k0 < K; k0 += 64) {
        __syncthreads();
        #pragma unroll
        for (int it = 0; it < 2; ++it) {
            int idx = it * 256 + tid;
            int m = idx >> 3, kc = idx & 7;
            uint4 v = *(const uint4*)(A + (size_t)(m0 + m) * K + k0 + kc * 8);
            *(uint4*)(&As[0] + (kc * 64 + (m ^ kc)) * 8) = v;
        }
        #pragma unroll
        for (int it = 0; it < NI; ++it) {
            int idx = it * 256 + tid;
            int n = idx >> 3, kc = idx & 7;
            int phys_g = kc * NT + (n ^ kc);
            *(uint4*)(&Bs[0][0] + phys_g * 8) =
                *(const uint4*)(Bt_h + (size_t)(n0 + n) * K + k0 + kc * 8);
            if constexpr (BSPLIT)
                *(uint4*)(&Bs[NPB - 1][0] + phys_g * 8) =
                    *(const uint4*)(Bt_l + (size_t)(n0 + n) * K + k0 + kc * 8);
        }
        __syncthreads();

        #pragma unroll
        for (int kt2 = 0; kt2 < 2; ++kt2) {
            const int kc = kt2 * 4 + fq;
            bf16x8 ah[2], bh[NI];
            #pragma unroll
            for (int mi = 0; mi < 2; ++mi)
                ah[mi] = *(const bf16x8*)(&As[0] + (kc * 64 + ((wm + mi * 16 + fm) ^ kc)) * 8);
            #pragma unroll
            for (int ni = 0; ni < NI; ++ni)
                bh[ni] = *(const bf16x8*)(&Bs[0][0] + (kc * NT + ((wn + ni * 16 + fm) ^ kc)) * 8);
            #pragma unroll
            for (int mi = 0; mi < 2; ++mi)
                #pragma unroll
                for (int ni = 0; ni < NI; ++ni)
                    acc[mi][ni] = __builtin_amdgcn_mfma_f32_16x16x32_bf16(
                        ah[mi], bh[ni], acc[mi][ni], 0, 0, 0);
            if constexpr (BSPLIT) {
                bf16x8 bl[NI];
                #pragma unroll
                for (int ni = 0; ni < NI; ++ni)
                    bl[ni] = *(const bf16x8*)(&Bs[NPB - 1][0] + (kc * NT + ((wn + ni * 16 + fm) ^ kc)) * 8);
                #pragma unroll
                for (int mi = 0; mi < 2; ++mi)
                    #pragma unroll
                    for (int ni = 0; ni < NI; ++ni)
                        acc[mi][ni] = __builtin_amdgcn_mfma_f32_16x16x32_bf16(
                            ah[mi], bl[ni], acc[mi][ni], 0, 0, 0);
            }
        }
    }

    // epilogue: C/D col=lane&15, row=fq*4+reg
    #pragma unroll
    for (int ni = 0; ni < NI; ++ni) {
        const int lcol = wn + ni * 16 + fm;
        const int col = n0 + lcol;
        const float bv = bias[col];
        // v-channel index within the 192-wide group (valid for NT=192 or 96)
        const int vl = (n0 % 192) + lcol - 128;
        #pragma unroll
        for (int mi = 0; mi < 2; ++mi) {
            const int rbase = m0 + wm + mi * 16 + fq * 4;
            if constexpr (VT) {
                if (vl >= 0) {
                    // tiled store: 4 consecutive jj at fixed dd -> one 8B
                    // tile at (jj>>2)*128 + dd*4; fm-lanes contiguous 128B.
                    int bb = rbase / 9216;
                    int rem = rbase - bb * 9216;
                    int ii = rem / 96;
                    int jj = rem - ii * 96;
                    int hh = vl >> 5, dd = vl & 31;
                    unsigned long long pk =
                          (unsigned long long)f2bf(acc[mi][ni][0] + bv)
                        | ((unsigned long long)f2bf(acc[mi][ni][1] + bv) << 16)
                        | ((unsigned long long)f2bf(acc[mi][ni][2] + bv) << 32)
                        | ((unsigned long long)f2bf(acc[mi][ni][3] + bv) << 48);
                    *(unsigned long long*)(vTout
                        + ((size_t)((bb * 96 + ii) * 6) + (n0 / 192) * 2 + hh) * 3072
                        + (size_t)(jj >> 2) * 128 + dd * 4) = pk;
                    continue;                    // v never read from qkvh
                }
            }
            #pragma unroll
            for (int r = 0; r < 4; ++r) {
                float val = acc[mi][ni][r] + bv;
                if constexpr (OUTBF)
                    ((ushort_t*)Cout)[(size_t)(rbase + r) * N + col] = f2bf(val);
                else
                    ((float*)Cout)[(size_t)(rbase + r) * N + col] = val;
            }
        }
    }
}

// ---------------------------------------------------------------------------
// Neighborhood attention v8t — row-paired hybrid, tiled-vT (UNCHANGED from
// R10, verified).
// ---------------------------------------------------------------------------
__global__ __launch_bounds__(384, 5) void na2d_kernel(
    const ushort_t* __restrict__ qkv, const ushort_t* __restrict__ vT,
    ushort_t* __restrict__ attn)
{
    __shared__ ushort_t Kb[2][96 * 40];    // [col][pad40], chunk-XOR swizzle
    __shared__ ushort_t Vtb[2][3072];      // linear tiled slice copy

    // bijective XCD-contiguity swizzle (1152 = 8 * 144)
    int phys = blockIdx.x;
    int idx = (phys & 7) * 144 + (phys >> 3);

    const int g = idx % 3; idx /= 3;       // g fastest: XCD load balance
    const int h = idx & 1; idx >>= 1;
    const int R = idx % 48;
    const int b = idx / 48;
    const int i0 = R * 2, i1 = i0 + 1;

    const int K = 7 + 2 * g, cc = K >> 1;
    int si0 = i0 - cc; if (si0 < 0) si0 = 0; if (si0 > H_ - K) si0 = H_ - K;
    int si1 = i1 - cc; if (si1 < 0) si1 = 0; if (si1 > H_ - K) si1 = H_ - K;
    const int off1 = si1 - si0;            // 0 or 1
    const int NTr = K + off1;              // staged rows

    const int tid = threadIdx.x;
    const int w = tid >> 6, lane = tid & 63;
    const int fm = lane & 15, fq = lane >> 4;
    const int pixbase = w * 16;

    int cb = (pixbase - cc) & ~7;          // aligned union-window base
    if (cb < 0) cb = 0; if (cb > 64) cb = 64;
    const int col0 = cb + fm, col1 = cb + 16 + fm;

    // per-lane softmax mask -> exp2 bias; depends only on j -> row-shared
    const int jlane = pixbase + fm;
    int sjl = jlane - cc; if (sjl < 0) sjl = 0; if (sjl > W_ - K) sjl = W_ - K;
    float b0[4], b1[4];
    #pragma unroll
    for (int r = 0; r < 4; ++r) {
        b0[r] = ((unsigned)(cb + fq * 4 + r - sjl)      < (unsigned)K) ? 0.f : -1e30f;
        b1[r] = ((unsigned)(cb + 16 + fq * 4 + r - sjl) < (unsigned)K) ? 0.f : -1e30f;
    }

    // Q B-frags for both rows: pixel j=jlane, dims fq*8..+8 (loop-invariant)
    const size_t rowstride = (size_t)W_ * QKVC;    // ushorts per image row
    const size_t qoff = (size_t)jlane * QKVC + g * 192 + h * 32 + fq * 8;
    const bf16x8 qfragA = *(const bf16x8*)(qkv + (size_t)(b * H_ + i0) * rowstride + qoff);
    const bf16x8 qfragB = *(const bf16x8*)(qkv + (size_t)(b * H_ + i1) * rowstride + qoff);

    // staging maps (coalesced: addr = base + tid*16B for both)
    const int scol = tid >> 2, sch = tid & 3;
    const size_t kgoff = (size_t)scol * QKVC + g * 192 + 64 + h * 32 + sch * 8;
    const int klds = scol * 40 + ((sch ^ (scol & 3)) << 3);
    const size_t vslice = ((size_t)((b * H_ + si0) * 6) + g * 2 + h) * 3072;

    f32x4 ya0 = {0.f,0.f,0.f,0.f}, ya1 = {0.f,0.f,0.f,0.f};
    f32x4 yb0 = {0.f,0.f,0.f,0.f}, yb1 = {0.f,0.f,0.f,0.f};
    float lsumA = 0.f, lsumB = 0.f;

    uint4 kv = *(const uint4*)(qkv + (size_t)(b * H_ + si0) * rowstride + kgoff);
    uint4 vv = *(const uint4*)(vT + vslice + (size_t)tid * 8);

    // shared softmax+PV body (verified v7 arithmetic)
    auto softmax_pv = [&](const f32x4& s0, const f32x4& s1, float& lsum,
                          const bf16x8& cv0, const bf16x8& cv1,
                          f32x4& y0, f32x4& y1) {
        unsigned short p00 = f2bf(fexp2(fmaf(s0[0], C2, b0[0])));
        unsigned short p01 = f2bf(fexp2(fmaf(s0[1], C2, b0[1])));
        unsigned short p02 = f2bf(fexp2(fmaf(s0[2], C2, b0[2])));
        unsigned short p03 = f2bf(fexp2(fmaf(s0[3], C2, b0[3])));
        unsigned short p10 = f2bf(fexp2(fmaf(s1[0], C2, b1[0])));
        unsigned short p11 = f2bf(fexp2(fmaf(s1[1], C2, b1[1])));
        unsigned short p12 = f2bf(fexp2(fmaf(s1[2], C2, b1[2])));
        unsigned short p13 = f2bf(fexp2(fmaf(s1[3], C2, b1[3])));
        lsum += (bf2f(p00) + bf2f(p01)) + (bf2f(p02) + bf2f(p03))
              + (bf2f(p10) + bf2f(p11)) + (bf2f(p12) + bf2f(p13));
        const bf16x8 pa = __builtin_bit_cast(bf16x8, (uint4){
            pack2(p00, p01), pack2(p02, p03),
            pack2(p10, p11), pack2(p12, p13)});
        y0 = __builtin_amdgcn_mfma_f32_16x16x32_bf16(pa, cv0, y0, 0, 0, 0);
        y1 = __builtin_amdgcn_mfma_f32_16x16x32_bf16(pa, cv1, y1, 0, 0, 0);
    };

    for (int t = 0; t < NTr; ++t) {
        *(uint4*)&Kb[t & 1][klds] = kv;
        *(uint4*)&Vtb[t & 1][tid * 8] = vv;
        if (t + 1 < NTr) {
            kv = *(const uint4*)(qkv + (size_t)(b * H_ + si0 + t + 1) * rowstride + kgoff);
            vv = *(const uint4*)(vT + vslice + (size_t)(t + 1) * 18432 + (size_t)tid * 8);
        }
        __syncthreads();

        // ---- shared LDS fragment reads ----
        bf16x8 kf0 = *(const bf16x8*)&Kb[t & 1][col0 * 40 + ((fq ^ (col0 & 3)) << 3)];
        bf16x8 kf1 = *(const bf16x8*)&Kb[t & 1][col1 * 40 + ((fq ^ (col1 & 3)) << 3)];
        // V B-frags from the tiled slice: cell (cb>>2)+fq (+4 for cols+16),
        // dims fm and fm+16 -> 4x ds_read_b64.
        const ushort_t* vbase = &Vtb[t & 1][((cb >> 2) + fq) * 128 + fm * 4];
        uint2 va0 = *(const uint2*)(vbase);            // cols cb+4fq..+3,  dim fm
        uint2 va1 = *(const uint2*)(vbase + 512);      // cols cb+16+4fq..+3, dim fm
        uint2 va2 = *(const uint2*)(vbase + 64);       // cols cb+4fq..+3,  dim fm+16
        uint2 va3 = *(const uint2*)(vbase + 512 + 64); // cols cb+16+4fq..+3, dim fm+16
        const bf16x8 cv0 = __builtin_bit_cast(bf16x8, (uint4){va0.x, va0.y, va1.x, va1.y});
        const bf16x8 cv1 = __builtin_bit_cast(bf16x8, (uint4){va2.x, va2.y, va3.x, va3.y});

        // ---- row A (valid t: 0..K-1) — wave-uniform guard ----
        if (t < K) {
            f32x4 s0 = __builtin_amdgcn_mfma_f32_16x16x32_bf16(
                kf0, qfragA, (f32x4){0.f, 0.f, 0.f, 0.f}, 0, 0, 0);
            f32x4 s1 = __builtin_amdgcn_mfma_f32_16x16x32_bf16(
                kf1, qfragA, (f32x4){0.f, 0.f, 0.f, 0.f}, 0, 0, 0);
            softmax_pv(s0, s1, lsumA, cv0, cv1, ya0, ya1);
        }
        // ---- row B (valid t: off1..off1+K-1; t<NTr implies t<off1+K) ----
        if (t >= off1) {
            f32x4 s0 = __builtin_amdgcn_mfma_f32_16x16x32_bf16(
                kf0, qfragB, (f32x4){0.f, 0.f, 0.f, 0.f}, 0, 0, 0);
            f32x4 s1 = __builtin_amdgcn_mfma_f32_16x16x32_bf16(
                kf1, qfragB, (f32x4){0.f, 0.f, 0.f, 0.f}, 0, 0, 0);
            softmax_pv(s0, s1, lsumB, cv0, cv1, yb0, yb1);
        }
    }

    // ---- reduce l + store, per row ----
    lsumA += __shfl_xor(lsumA, 16);
    lsumA += __shfl_xor(lsumA, 32);        // l[j=fm], uniform over fq
    lsumB += __shfl_xor(lsumB, 16);
    lsumB += __shfl_xor(lsumB, 32);

    #pragma unroll
    for (int r = 0; r < 4; ++r) {
        const int j = pixbase + fq * 4 + r;
        const float lA = __shfl(lsumA, fq * 4 + r);
        const float lB = __shfl(lsumB, fq * 4 + r);
        const float invA = 1.f / lA, invB = 1.f / lB;
        const size_t oA = (size_t)((b * H_ + i0) * W_ + j) * C_ + g * 64 + h * 32 + fm;
        const size_t oB = (size_t)((b * H_ + i1) * W_ + j) * C_ + g * 64 + h * 32 + fm;
        attn[oA]      = f2bf(ya0[r] * invA);
        attn[oA + 16] = f2bf(ya1[r] * invA);
        attn[oB]      = f2bf(yb0[r] * invB);
        attn[oB + 16] = f2bf(yb1[r] * invB);
    }
}

// ---------------------------------------------------------------------------
extern "C" void kernel_launch(void* const* d_in, const int* in_sizes, int n_in,
                              void* d_out, int out_size, void* d_ws, size_t ws_size,
                              hipStream_t stream)
{
    const float* x      = (const float*)d_in[0];
    const float* w_qkv  = (const float*)d_in[1];
    const float* b_qkv  = (const float*)d_in[2];
    const float* w_proj = (const float*)d_in[3];
    const float* b_proj = (const float*)d_in[4];
    float* out = (float*)d_out;

    // Workspace: [qkvh 42.5MB][xh/attn bf16 14.2MB aliased][weights][vT 14.2MB]
    char* ws = (char*)d_ws;
    ushort_t* qkvh  = (ushort_t*)ws;
    char*     reg1  = ws + (size_t)NPIX * QKVC * 2;
    ushort_t* xh    = (ushort_t*)reg1;            // dead after GEMM1
    ushort_t* attn  = (ushort_t*)reg1;            // aliases xh
    char*     wbase = reg1 + (size_t)NPIX * C_ * 2;
    ushort_t* wqt   = (ushort_t*)wbase;
    ushort_t* wpt_h = (ushort_t*)(wbase + 576 * 192 * 2);
    ushort_t* wpt_l = (ushort_t*)(wbase + 576 * 192 * 2 + 192 * 192 * 2);
    ushort_t* vT    = (ushort_t*)(wbase + 576 * 192 * 2 + 2 * 192 * 192 * 2);

    // 0) all fp32->bf16 conversions in one dispatch
    convert_all_kernel<<<7488, 256, 0, stream>>>(
        x, w_qkv, w_proj, xh, wqt, wpt_h, wpt_l, NPIX * C_ / 4);

    // 1) qkv = xh @ w_qkv + b_qkv (bf16, q/k only) + tiled vT (coalesced)
    //    R12: NT=96 -> LDS 20KB -> 8 blocks/CU; grid 3456 = 8 * 432
    gemm_mfma2_kernel<false, true, true, 96><<<(NPIX / 64) * (QKVC / 96), 256, 0, stream>>>(
        xh, wqt, nullptr, b_qkv, qkvh, vT, NPIX, QKVC, C_);

    // 2) neighborhood attention (row-paired hybrid, tiled-vT): 1152 x 384
    na2d_kernel<<<1152, 384, 0, stream>>>(qkvh, vT, attn);

    // 3) out = attn @ w_proj + b_proj (A bf16, B split-bf16 2-pass, N-tile 96)
    //    grid 1152 = 8 * 144 (XCD-swizzled), R10-exact
    gemm_mfma2_kernel<true, false, false, 96><<<(NPIX / 64) * (C_ / 96), 256, 0, stream>>>(
        attn, wpt_h, wpt_l, b_proj, out, nullptr, NPIX, C_, C_);
}